// Round 12
// baseline (779.063 us; speedup 1.0000x reference)
//
#include <hip/hip_runtime.h>
#include <hip/hip_bf16.h>

typedef _Float16 half8 __attribute__((ext_vector_type(8)));
typedef _Float16 half4 __attribute__((ext_vector_type(4)));
typedef _Float16 half2v __attribute__((ext_vector_type(2)));
typedef __fp16 fp16x2 __attribute__((ext_vector_type(2)));
typedef float f32x4 __attribute__((ext_vector_type(4)));

#define BH_ 64
#define L_ 1024
#define DK_ 64

__device__ __forceinline__ unsigned short f2h(float f) {
    _Float16 h = (_Float16)f;
    return __builtin_bit_cast(unsigned short, h);
}
__device__ __forceinline__ unsigned int pk2h(float a, float b) {
    fp16x2 h = __builtin_amdgcn_cvt_pkrtz(a, b);
    return __builtin_bit_cast(unsigned int, h);
}

// ---------------- prep: K -> fp16 ----------------
__global__ void prep_k(const float* __restrict__ K, unsigned short* __restrict__ Kh) {
    int idx = blockIdx.x * 256 + threadIdx.x;
    float4 v = reinterpret_cast<const float4*>(K)[idx];
    ushort4 o;
    o.x = f2h(v.x); o.y = f2h(v.y); o.z = f2h(v.z); o.w = f2h(v.w);
    reinterpret_cast<ushort4*>(Kh)[idx] = o;
}

// ---------------- prep: V -> Vt fp16 transposed [bh][n][k] ----------------
__global__ void prep_v(const float* __restrict__ V, unsigned short* __restrict__ Vt) {
    __shared__ float lds[64][65];
    int bh = blockIdx.x >> 4, kt = blockIdx.x & 15;
    int t = threadIdx.x;
    const float* Vb = V + ((size_t)bh * L_ + kt * 64) * DK_;
#pragma unroll
    for (int it = 0; it < 4; ++it) {
        int idx = it * 256 + t;
        int row = idx >> 4, c4 = idx & 15;
        float4 v = reinterpret_cast<const float4*>(Vb + (size_t)row * DK_)[c4];
        lds[row][c4 * 4 + 0] = v.x; lds[row][c4 * 4 + 1] = v.y;
        lds[row][c4 * 4 + 2] = v.z; lds[row][c4 * 4 + 3] = v.w;
    }
    __syncthreads();
    unsigned short* Vtb = Vt + (size_t)bh * 64 * L_ + kt * 64;
#pragma unroll
    for (int it = 0; it < 4; ++it) {
        int idx = it * 256 + t;
        int n = idx >> 4, c4 = idx & 15;
        ushort4 o;
        o.x = f2h(lds[c4 * 4 + 0][n]);
        o.y = f2h(lds[c4 * 4 + 1][n]);
        o.z = f2h(lds[c4 * 4 + 2][n]);
        o.w = f2h(lds[c4 * 4 + 3][n]);
        *reinterpret_cast<ushort4*>(Vtb + (size_t)n * L_ + c4 * 4) = o;
    }
}

// ---------------- ablation body: MODE 0=full 1=nostore 2=nomask 3=noqk 4=nopv
template<int MODE>
__device__ __forceinline__ void attn_body(
    const float* __restrict__ Q, const int* __restrict__ mask,
    const unsigned short* __restrict__ Kh, const unsigned short* __restrict__ Vt,
    float* __restrict__ ctx_out, float* __restrict__ attn_out)
{
    const int qt = blockIdx.x, bh = blockIdx.y;
    const int tid = threadIdx.x;
    const int w = tid >> 6;
    const int lane = tid & 63;
    const int lg = lane >> 4, lr = lane & 15;
    const int q0 = qt * 16;

    __shared__ unsigned char mnib[16][272];
    __shared__ float red[2][4][16];
    __shared__ union {
        unsigned short p[16][1024];
        float ctxbuf[4][16][68];
    } u;

    auto paddr = [&](int row, int col) -> unsigned short* {
        unsigned byte = (unsigned)row * 2048u +
                        (((unsigned)col * 2u) ^ (((unsigned)(row & 7)) << 4));
        return (unsigned short*)((char*)&u.p[0][0] + byte);
    };

    // ---- phase 0: mask rows, wave-sequential bursts -> nibble LDS ----
#pragma unroll
    for (int rr = 0; rr < 4; ++rr) {
        const int row = w * 4 + rr;
        const int* mrow = mask + ((size_t)bh * L_ + q0 + row) * L_;
#pragma unroll
        for (int j = 0; j < 4; ++j) {
            unsigned char nib;
            if constexpr (MODE == 2) {
                nib = 0;
            } else {
                int4 v = *reinterpret_cast<const int4*>(mrow + j * 256 + lane * 4);
                nib = (unsigned char)(unsigned(v.x != 0)
                    | (unsigned(v.y != 0) << 1)
                    | (unsigned(v.z != 0) << 2)
                    | (unsigned(v.w != 0) << 3));
            }
            mnib[row][j * 64 + lane] = nib;
        }
    }

    half8 qh[2];
    {
        const float* qp = Q + ((size_t)bh * L_ + q0 + lr) * DK_ + lg * 8;
#pragma unroll
        for (int f = 0; f < 2; ++f) {
            float4 a = *reinterpret_cast<const float4*>(qp + f * 32);
            float4 b = *reinterpret_cast<const float4*>(qp + f * 32 + 4);
            qh[f][0] = (_Float16)a.x; qh[f][1] = (_Float16)a.y;
            qh[f][2] = (_Float16)a.z; qh[f][3] = (_Float16)a.w;
            qh[f][4] = (_Float16)b.x; qh[f][5] = (_Float16)b.y;
            qh[f][6] = (_Float16)b.z; qh[f][7] = (_Float16)b.w;
        }
    }
    __syncthreads();

    const unsigned short* kp = Kh + ((size_t)bh * L_ + w * 256 + lr) * DK_ + lg * 8;
    const unsigned char* mn = &mnib[lr][w * 64];
    unsigned int sh[16][2];
    float mx = -INFINITY;

    half8 kc0, kc1;
    if constexpr (MODE != 3) {
        kc0 = *reinterpret_cast<const half8*>(kp);
        kc1 = *reinterpret_cast<const half8*>(kp + 32);
    }

#pragma unroll
    for (int tt = 0; tt < 16; ++tt) {
        f32x4 acc;
        if constexpr (MODE != 3) {
            half8 kn0 = kc0, kn1 = kc1;
            if (tt < 15) {
                kn0 = *reinterpret_cast<const half8*>(kp + (tt + 1) * 1024);
                kn1 = *reinterpret_cast<const half8*>(kp + (tt + 1) * 1024 + 32);
            }
            acc = (f32x4){0.f, 0.f, 0.f, 0.f};
            acc = __builtin_amdgcn_mfma_f32_16x16x32_f16(kc0, qh[0], acc, 0, 0, 0);
            acc = __builtin_amdgcn_mfma_f32_16x16x32_f16(kc1, qh[1], acc, 0, 0, 0);
            kc0 = kn0; kc1 = kn1;
        } else {
            acc = (f32x4){1.f, 1.f, 1.f, 1.f};
        }
        unsigned nv = *reinterpret_cast<const unsigned int*>(&mn[tt * 4]);
        unsigned nib = (nv >> (lg * 8)) & 0xFu;
        float s0 = (nib & 1u) ? -INFINITY : 0.25f * acc[0];
        float s1 = (nib & 2u) ? -INFINITY : 0.25f * acc[1];
        float s2 = (nib & 4u) ? -INFINITY : 0.25f * acc[2];
        float s3 = (nib & 8u) ? -INFINITY : 0.25f * acc[3];
        sh[tt][0] = pk2h(s0, s1);
        sh[tt][1] = pk2h(s2, s3);
        mx = fmaxf(mx, fmaxf(fmaxf(s0, s1), fmaxf(s2, s3)));
    }

    mx = fmaxf(mx, __shfl_xor(mx, 16));
    mx = fmaxf(mx, __shfl_xor(mx, 32));
    if (lane < 16) red[0][w][lr] = mx;
    __syncthreads();
    const float gm = fmaxf(fmaxf(red[0][0][lr], red[0][1][lr]),
                           fmaxf(red[0][2][lr], red[0][3][lr]));

    float lsum = 0.f;
#pragma unroll
    for (int tt = 0; tt < 16; ++tt) {
        half2v a = __builtin_bit_cast(half2v, sh[tt][0]);
        half2v b = __builtin_bit_cast(half2v, sh[tt][1]);
        float p0 = __expf((float)a[0] - gm);
        float p1 = __expf((float)a[1] - gm);
        float p2 = __expf((float)b[0] - gm);
        float p3 = __expf((float)b[1] - gm);
        lsum += (p0 + p1) + (p2 + p3);
        sh[tt][0] = pk2h(p0, p1);
        sh[tt][1] = pk2h(p2, p3);
    }
    lsum += __shfl_xor(lsum, 16);
    lsum += __shfl_xor(lsum, 32);
    if (lane < 16) red[1][w][lr] = lsum;

#pragma unroll
    for (int tt = 0; tt < 16; ++tt) {
        uint2 pr; pr.x = sh[tt][0]; pr.y = sh[tt][1];
        *reinterpret_cast<uint2*>(paddr(lr, w * 256 + tt * 16 + lg * 4)) = pr;
    }

    f32x4 cacc[4] = {{0,0,0,0},{0,0,0,0},{0,0,0,0},{0,0,0,0}};
    if constexpr (MODE != 4) {
        const unsigned short* vp = Vt + ((size_t)bh * 64 + lr) * L_ + w * 256 + lg * 8;
        half8 vb0 = *reinterpret_cast<const half8*>(vp);
        half8 vb1 = *reinterpret_cast<const half8*>(vp + 16384);
        half8 vb2 = *reinterpret_cast<const half8*>(vp + 32768);
        half8 vb3 = *reinterpret_cast<const half8*>(vp + 49152);
#pragma unroll
        for (int c = 0; c < 8; ++c) {
            half8 vn0 = vb0, vn1 = vb1, vn2 = vb2, vn3 = vb3;
            if (c < 7) {
                vn0 = *reinterpret_cast<const half8*>(vp + (c + 1) * 32);
                vn1 = *reinterpret_cast<const half8*>(vp + 16384 + (c + 1) * 32);
                vn2 = *reinterpret_cast<const half8*>(vp + 32768 + (c + 1) * 32);
                vn3 = *reinterpret_cast<const half8*>(vp + 49152 + (c + 1) * 32);
            }
            half8 pa = *reinterpret_cast<const half8*>(paddr(lr, w * 256 + c * 32 + lg * 8));
            cacc[0] = __builtin_amdgcn_mfma_f32_16x16x32_f16(pa, vb0, cacc[0], 0, 0, 0);
            cacc[1] = __builtin_amdgcn_mfma_f32_16x16x32_f16(pa, vb1, cacc[1], 0, 0, 0);
            cacc[2] = __builtin_amdgcn_mfma_f32_16x16x32_f16(pa, vb2, cacc[2], 0, 0, 0);
            cacc[3] = __builtin_amdgcn_mfma_f32_16x16x32_f16(pa, vb3, cacc[3], 0, 0, 0);
            vb0 = vn0; vb1 = vn1; vb2 = vn2; vb3 = vn3;
        }
    }

    __syncthreads();

    // ---- attn store pass (or asm sink in MODE 1) ----
#pragma unroll
    for (int rr = 0; rr < 4; ++rr) {
        const int q = w * 4 + rr;
        const float rq = 1.0f / (red[1][0][q] + red[1][1][q] +
                                 red[1][2][q] + red[1][3][q]);
        float* orow = attn_out + ((size_t)bh * L_ + q0 + q) * L_;
#pragma unroll
        for (int i = 0; i < 4; ++i) {
            const int col = i * 256 + lane * 4;
            half4 v = *reinterpret_cast<const half4*>(paddr(q, col));
            float4 o;
            o.x = (float)v[0] * rq; o.y = (float)v[1] * rq;
            o.z = (float)v[2] * rq; o.w = (float)v[3] * rq;
            if constexpr (MODE == 1) {
                asm volatile("" :: "v"(o.x), "v"(o.y), "v"(o.z), "v"(o.w));
            } else {
                *reinterpret_cast<float4*>(orow + col) = o;
            }
        }
    }

    __syncthreads();

#pragma unroll
    for (int nt = 0; nt < 4; ++nt)
#pragma unroll
        for (int r = 0; r < 4; ++r)
            u.ctxbuf[w][lg * 4 + r][nt * 16 + lr] = cacc[nt][r];
    __syncthreads();
    {
        int e = tid * 4;
        int q = e >> 6, n = e & 63;
        float gs = red[1][0][q] + red[1][1][q] + red[1][2][q] + red[1][3][q];
        float rq = 1.0f / gs;
        float4 a0 = *reinterpret_cast<float4*>(&u.ctxbuf[0][q][n]);
        float4 a1 = *reinterpret_cast<float4*>(&u.ctxbuf[1][q][n]);
        float4 a2 = *reinterpret_cast<float4*>(&u.ctxbuf[2][q][n]);
        float4 a3 = *reinterpret_cast<float4*>(&u.ctxbuf[3][q][n]);
        float4 o;
        o.x = (a0.x + a1.x + a2.x + a3.x) * rq;
        o.y = (a0.y + a1.y + a2.y + a3.y) * rq;
        o.z = (a0.z + a1.z + a2.z + a3.z) * rq;
        o.w = (a0.w + a1.w + a2.w + a3.w) * rq;
        *reinterpret_cast<float4*>(&ctx_out[((size_t)bh * L_ + q0 + q) * DK_ + n]) = o;
    }
}

#define ARGS const float* __restrict__ Q, const int* __restrict__ mask, \
             const unsigned short* __restrict__ Kh, const unsigned short* __restrict__ Vt, \
             float* __restrict__ ctx_out, float* __restrict__ attn_out

__global__ __launch_bounds__(256, 4) void attn_nostore(ARGS) { attn_body<1>(Q, mask, Kh, Vt, ctx_out, attn_out); }
__global__ __launch_bounds__(256, 4) void attn_nomask(ARGS)  { attn_body<2>(Q, mask, Kh, Vt, ctx_out, attn_out); }
__global__ __launch_bounds__(256, 4) void attn_noqk(ARGS)    { attn_body<3>(Q, mask, Kh, Vt, ctx_out, attn_out); }
__global__ __launch_bounds__(256, 4) void attn_nopv(ARGS)    { attn_body<4>(Q, mask, Kh, Vt, ctx_out, attn_out); }
__global__ __launch_bounds__(256, 4) void attn_full(ARGS)    { attn_body<0>(Q, mask, Kh, Vt, ctx_out, attn_out); }

extern "C" void kernel_launch(void* const* d_in, const int* in_sizes, int n_in,
                              void* d_out, int out_size, void* d_ws, size_t ws_size,
                              hipStream_t stream) {
    const float* Q = (const float*)d_in[0];
    const float* K = (const float*)d_in[1];
    const float* V = (const float*)d_in[2];
    const int* mask = (const int*)d_in[3];
    float* ctx_out = (float*)d_out;
    float* attn_out = ctx_out + (size_t)BH_ * L_ * DK_;

    unsigned short* Kh = (unsigned short*)d_ws;
    unsigned short* Vt = Kh + (size_t)BH_ * L_ * DK_;

    hipLaunchKernelGGL(prep_k, dim3(4096), dim3(256), 0, stream, K, Kh);
    hipLaunchKernelGGL(prep_v, dim3(1024), dim3(256), 0, stream, V, Vt);
    // ablation dispatches (full grid each; outputs garbage, overwritten below)
    hipLaunchKernelGGL(attn_nostore, dim3(64, 64), dim3(256), 0, stream,
                       Q, mask, Kh, Vt, ctx_out, attn_out);
    hipLaunchKernelGGL(attn_nomask, dim3(64, 64), dim3(256), 0, stream,
                       Q, mask, Kh, Vt, ctx_out, attn_out);
    hipLaunchKernelGGL(attn_noqk, dim3(64, 64), dim3(256), 0, stream,
                       Q, mask, Kh, Vt, ctx_out, attn_out);
    hipLaunchKernelGGL(attn_nopv, dim3(64, 64), dim3(256), 0, stream,
                       Q, mask, Kh, Vt, ctx_out, attn_out);
    // final correct pass (control timing + overwrites all outputs)
    hipLaunchKernelGGL(attn_full, dim3(64, 64), dim3(256), 0, stream,
                       Q, mask, Kh, Vt, ctx_out, attn_out);
}

// Round 13
// 204.547 us; speedup vs baseline: 3.8087x; 3.8087x over previous
//
#include <hip/hip_runtime.h>
#include <hip/hip_bf16.h>

typedef _Float16 half8 __attribute__((ext_vector_type(8)));
typedef _Float16 half4 __attribute__((ext_vector_type(4)));
typedef _Float16 half2v __attribute__((ext_vector_type(2)));
typedef __fp16 fp16x2 __attribute__((ext_vector_type(2)));
typedef float f32x4 __attribute__((ext_vector_type(4)));

#define BH_ 64
#define L_ 1024
#define DK_ 64

__device__ __forceinline__ unsigned short f2h(float f) {
    _Float16 h = (_Float16)f;
    return __builtin_bit_cast(unsigned short, h);
}
__device__ __forceinline__ unsigned int pk2h(float a, float b) {
    fp16x2 h = __builtin_amdgcn_cvt_pkrtz(a, b);
    return __builtin_bit_cast(unsigned int, h);
}

// ---------------- prep: K -> fp16 ----------------
__global__ void prep_k(const float* __restrict__ K, unsigned short* __restrict__ Kh) {
    int idx = blockIdx.x * 256 + threadIdx.x;
    float4 v = reinterpret_cast<const float4*>(K)[idx];
    ushort4 o;
    o.x = f2h(v.x); o.y = f2h(v.y); o.z = f2h(v.z); o.w = f2h(v.w);
    reinterpret_cast<ushort4*>(Kh)[idx] = o;
}

// ---------------- prep: V -> Vt fp16 transposed [bh][n][k] ----------------
__global__ void prep_v(const float* __restrict__ V, unsigned short* __restrict__ Vt) {
    __shared__ float lds[64][65];
    int bh = blockIdx.x >> 4, kt = blockIdx.x & 15;
    int t = threadIdx.x;
    const float* Vb = V + ((size_t)bh * L_ + kt * 64) * DK_;
#pragma unroll
    for (int it = 0; it < 4; ++it) {
        int idx = it * 256 + t;
        int row = idx >> 4, c4 = idx & 15;
        float4 v = reinterpret_cast<const float4*>(Vb + (size_t)row * DK_)[c4];
        lds[row][c4 * 4 + 0] = v.x; lds[row][c4 * 4 + 1] = v.y;
        lds[row][c4 * 4 + 2] = v.z; lds[row][c4 * 4 + 3] = v.w;
    }
    __syncthreads();
    unsigned short* Vtb = Vt + (size_t)bh * 64 * L_ + kt * 64;
#pragma unroll
    for (int it = 0; it < 4; ++it) {
        int idx = it * 256 + t;
        int n = idx >> 4, c4 = idx & 15;
        ushort4 o;
        o.x = f2h(lds[c4 * 4 + 0][n]);
        o.y = f2h(lds[c4 * 4 + 1][n]);
        o.z = f2h(lds[c4 * 4 + 2][n]);
        o.w = f2h(lds[c4 * 4 + 3][n]);
        *reinterpret_cast<ushort4*>(Vtb + (size_t)n * L_ + c4 * 4) = o;
    }
}

// ---------------- main fused attention ----------------
// R12 ablation: phase times are ADDITIVE (convoy effect) - the store drain
// before the union-reuse barrier holds all 4 WG slots per CU, so no WG can
// start its read phase while stores drain. Fix: read p into REGISTERS before
// the LDS union is reused, then issue all global stores LAST with no trailing
// barrier -> s_endpgm retires the WG immediately, slot frees, next WG's mask
// reads overlap this WG's draining stores.
__global__ __launch_bounds__(256, 4) void attn_main(
    const float* __restrict__ Q, const int* __restrict__ mask,
    const unsigned short* __restrict__ Kh, const unsigned short* __restrict__ Vt,
    float* __restrict__ ctx_out, float* __restrict__ attn_out)
{
    const int qt = blockIdx.x, bh = blockIdx.y;
    const int tid = threadIdx.x;
    const int w = tid >> 6;
    const int lane = tid & 63;
    const int lg = lane >> 4, lr = lane & 15;
    const int q0 = qt * 16;

    __shared__ unsigned char mnib[16][272];
    __shared__ float red[2][4][16];
    __shared__ union {
        unsigned short p[16][1024];  // swizzled
        float ctxbuf[4][16][68];
    } u;

    auto paddr = [&](int row, int col) -> unsigned short* {
        unsigned byte = (unsigned)row * 2048u +
                        (((unsigned)col * 2u) ^ (((unsigned)(row & 7)) << 4));
        return (unsigned short*)((char*)&u.p[0][0] + byte);
    };

    // ---- phase 0: mask rows, wave-sequential bursts -> nibble LDS ----
#pragma unroll
    for (int rr = 0; rr < 4; ++rr) {
        const int row = w * 4 + rr;
        const int* mrow = mask + ((size_t)bh * L_ + q0 + row) * L_;
#pragma unroll
        for (int j = 0; j < 4; ++j) {
            int4 v = *reinterpret_cast<const int4*>(mrow + j * 256 + lane * 4);
            unsigned nib = unsigned(v.x != 0)
                         | (unsigned(v.y != 0) << 1)
                         | (unsigned(v.z != 0) << 2)
                         | (unsigned(v.w != 0) << 3);
            mnib[row][j * 64 + lane] = (unsigned char)nib;
        }
    }

    half8 qh[2];
    {
        const float* qp = Q + ((size_t)bh * L_ + q0 + lr) * DK_ + lg * 8;
#pragma unroll
        for (int f = 0; f < 2; ++f) {
            float4 a = *reinterpret_cast<const float4*>(qp + f * 32);
            float4 b = *reinterpret_cast<const float4*>(qp + f * 32 + 4);
            qh[f][0] = (_Float16)a.x; qh[f][1] = (_Float16)a.y;
            qh[f][2] = (_Float16)a.z; qh[f][3] = (_Float16)a.w;
            qh[f][4] = (_Float16)b.x; qh[f][5] = (_Float16)b.y;
            qh[f][6] = (_Float16)b.z; qh[f][7] = (_Float16)b.w;
        }
    }
    __syncthreads();   // mnib ready

    // ---- QK^T: K depth-2 prefetch (L2-resident), mask nibble per tile ----
    const unsigned short* kp = Kh + ((size_t)bh * L_ + w * 256 + lr) * DK_ + lg * 8;
    const unsigned char* mn = &mnib[lr][w * 64];
    unsigned int sh[16][2];
    float mx = -INFINITY;

    half8 kc0 = *reinterpret_cast<const half8*>(kp);
    half8 kc1 = *reinterpret_cast<const half8*>(kp + 32);

#pragma unroll
    for (int tt = 0; tt < 16; ++tt) {
        half8 kn0 = kc0, kn1 = kc1;
        if (tt < 15) {
            kn0 = *reinterpret_cast<const half8*>(kp + (tt + 1) * 1024);
            kn1 = *reinterpret_cast<const half8*>(kp + (tt + 1) * 1024 + 32);
        }
        f32x4 acc = {0.f, 0.f, 0.f, 0.f};
        acc = __builtin_amdgcn_mfma_f32_16x16x32_f16(kc0, qh[0], acc, 0, 0, 0);
        acc = __builtin_amdgcn_mfma_f32_16x16x32_f16(kc1, qh[1], acc, 0, 0, 0);
        unsigned nv = *reinterpret_cast<const unsigned int*>(&mn[tt * 4]);
        unsigned nib = (nv >> (lg * 8)) & 0xFu;
        float s0 = (nib & 1u) ? -INFINITY : 0.25f * acc[0];
        float s1 = (nib & 2u) ? -INFINITY : 0.25f * acc[1];
        float s2 = (nib & 4u) ? -INFINITY : 0.25f * acc[2];
        float s3 = (nib & 8u) ? -INFINITY : 0.25f * acc[3];
        sh[tt][0] = pk2h(s0, s1);
        sh[tt][1] = pk2h(s2, s3);
        mx = fmaxf(mx, fmaxf(fmaxf(s0, s1), fmaxf(s2, s3)));
        kc0 = kn0; kc1 = kn1;
    }

    // ---- softmax: row max ----
    mx = fmaxf(mx, __shfl_xor(mx, 16));
    mx = fmaxf(mx, __shfl_xor(mx, 32));
    if (lane < 16) red[0][w][lr] = mx;
    __syncthreads();
    const float gm = fmaxf(fmaxf(red[0][0][lr], red[0][1][lr]),
                           fmaxf(red[0][2][lr], red[0][3][lr]));

    // ---- exp + row sum; p stays packed fp16 (unnormalized) ----
    float lsum = 0.f;
#pragma unroll
    for (int tt = 0; tt < 16; ++tt) {
        half2v a = __builtin_bit_cast(half2v, sh[tt][0]);
        half2v b = __builtin_bit_cast(half2v, sh[tt][1]);
        float p0 = __expf((float)a[0] - gm);
        float p1 = __expf((float)a[1] - gm);
        float p2 = __expf((float)b[0] - gm);
        float p3 = __expf((float)b[1] - gm);
        lsum += (p0 + p1) + (p2 + p3);
        sh[tt][0] = pk2h(p0, p1);
        sh[tt][1] = pk2h(p2, p3);
    }
    lsum += __shfl_xor(lsum, 16);
    lsum += __shfl_xor(lsum, 32);
    if (lane < 16) red[1][w][lr] = lsum;

    // ---- p -> swizzled LDS (wave-private strip) ----
#pragma unroll
    for (int tt = 0; tt < 16; ++tt) {
        uint2 pr; pr.x = sh[tt][0]; pr.y = sh[tt][1];
        *reinterpret_cast<uint2*>(paddr(lr, w * 256 + tt * 16 + lg * 4)) = pr;
    }

    // ---- PV: read p from LDS, V depth-1 prefetch (L2-resident) ----
    const unsigned short* vp = Vt + ((size_t)bh * 64 + lr) * L_ + w * 256 + lg * 8;
    f32x4 cacc[4] = {{0,0,0,0},{0,0,0,0},{0,0,0,0},{0,0,0,0}};
    half8 vb0 = *reinterpret_cast<const half8*>(vp);
    half8 vb1 = *reinterpret_cast<const half8*>(vp + 16384);
    half8 vb2 = *reinterpret_cast<const half8*>(vp + 32768);
    half8 vb3 = *reinterpret_cast<const half8*>(vp + 49152);

#pragma unroll
    for (int c = 0; c < 8; ++c) {
        half8 vn0 = vb0, vn1 = vb1, vn2 = vb2, vn3 = vb3;
        if (c < 7) {
            vn0 = *reinterpret_cast<const half8*>(vp + (c + 1) * 32);
            vn1 = *reinterpret_cast<const half8*>(vp + 16384 + (c + 1) * 32);
            vn2 = *reinterpret_cast<const half8*>(vp + 32768 + (c + 1) * 32);
            vn3 = *reinterpret_cast<const half8*>(vp + 49152 + (c + 1) * 32);
        }
        half8 pa = *reinterpret_cast<const half8*>(paddr(lr, w * 256 + c * 32 + lg * 8));
        cacc[0] = __builtin_amdgcn_mfma_f32_16x16x32_f16(pa, vb0, cacc[0], 0, 0, 0);
        cacc[1] = __builtin_amdgcn_mfma_f32_16x16x32_f16(pa, vb1, cacc[1], 0, 0, 0);
        cacc[2] = __builtin_amdgcn_mfma_f32_16x16x32_f16(pa, vb2, cacc[2], 0, 0, 0);
        cacc[3] = __builtin_amdgcn_mfma_f32_16x16x32_f16(pa, vb3, cacc[3], 0, 0, 0);
        vb0 = vn0; vb1 = vn1; vb2 = vn2; vb3 = vn3;
    }

    __syncthreads();   // all p strips + red[1] visible

    // ---- pull attn-store data into REGISTERS (p dies after this) ----
    half4 preg[4][4];
    float rqv[4];
#pragma unroll
    for (int rr = 0; rr < 4; ++rr) {
        const int q = w * 4 + rr;
        rqv[rr] = 1.0f / (red[1][0][q] + red[1][1][q] +
                          red[1][2][q] + red[1][3][q]);
#pragma unroll
        for (int i = 0; i < 4; ++i)
            preg[rr][i] = *reinterpret_cast<const half4*>(paddr(q, i * 256 + lane * 4));
    }

    __syncthreads();   // p reads done -> ctxbuf may overwrite

    // ---- combine partial contexts across waves, ctx store ----
#pragma unroll
    for (int nt = 0; nt < 4; ++nt)
#pragma unroll
        for (int r = 0; r < 4; ++r)
            u.ctxbuf[w][lg * 4 + r][nt * 16 + lr] = cacc[nt][r];
    __syncthreads();
    {
        int e = tid * 4;
        int q = e >> 6, n = e & 63;
        float gs = red[1][0][q] + red[1][1][q] + red[1][2][q] + red[1][3][q];
        float rq = 1.0f / gs;
        float4 a0 = *reinterpret_cast<float4*>(&u.ctxbuf[0][q][n]);
        float4 a1 = *reinterpret_cast<float4*>(&u.ctxbuf[1][q][n]);
        float4 a2 = *reinterpret_cast<float4*>(&u.ctxbuf[2][q][n]);
        float4 a3 = *reinterpret_cast<float4*>(&u.ctxbuf[3][q][n]);
        float4 o;
        o.x = (a0.x + a1.x + a2.x + a3.x) * rq;
        o.y = (a0.y + a1.y + a2.y + a3.y) * rq;
        o.z = (a0.z + a1.z + a2.z + a3.z) * rq;
        o.w = (a0.w + a1.w + a2.w + a3.w) * rq;
        *reinterpret_cast<float4*>(&ctx_out[((size_t)bh * L_ + q0 + q) * DK_ + n]) = o;
    }

    // ---- attn stores LAST, fire-and-forget, NO trailing barrier ----
    // wave w stores rows w*4..w*4+3; per row 4 x (1KB contiguous, lane*16B)
#pragma unroll
    for (int rr = 0; rr < 4; ++rr) {
        const int q = w * 4 + rr;
        const float rq = rqv[rr];
        float* orow = attn_out + ((size_t)bh * L_ + q0 + q) * L_;
#pragma unroll
        for (int i = 0; i < 4; ++i) {
            half4 v = preg[rr][i];
            float4 o;
            o.x = (float)v[0] * rq; o.y = (float)v[1] * rq;
            o.z = (float)v[2] * rq; o.w = (float)v[3] * rq;
            *reinterpret_cast<float4*>(orow + i * 256 + lane * 4) = o;
        }
    }
    // s_endpgm: WG retires while stores drain; slot frees for next WG's reads
}

extern "C" void kernel_launch(void* const* d_in, const int* in_sizes, int n_in,
                              void* d_out, int out_size, void* d_ws, size_t ws_size,
                              hipStream_t stream) {
    const float* Q = (const float*)d_in[0];
    const float* K = (const float*)d_in[1];
    const float* V = (const float*)d_in[2];
    const int* mask = (const int*)d_in[3];
    float* ctx_out = (float*)d_out;
    float* attn_out = ctx_out + (size_t)BH_ * L_ * DK_;

    unsigned short* Kh = (unsigned short*)d_ws;
    unsigned short* Vt = Kh + (size_t)BH_ * L_ * DK_;

    hipLaunchKernelGGL(prep_k, dim3(4096), dim3(256), 0, stream, K, Kh);
    hipLaunchKernelGGL(prep_v, dim3(1024), dim3(256), 0, stream, V, Vt);
    hipLaunchKernelGGL(attn_main, dim3(64, 64), dim3(256), 0, stream,
                       Q, mask, Kh, Vt, ctx_out, attn_out);
}